// Round 1
// baseline (6097.426 us; speedup 1.0000x reference)
//
#include <hip/hip_runtime.h>
#include <math.h>

#define LSEQ   2048
#define DMODEL 1024
#define DINNER 2048
#define DSTATE 16
#define DTRANK 64
#define NVOCAB 50264

__device__ __forceinline__ float sp_softplus(float x) {
    return fmaxf(x, 0.f) + log1pf(__expf(-fabsf(x)));
}
__device__ __forceinline__ float silu_f(float x) {
    return x / (1.f + __expf(-x));
}

// ---------------- embedding gather ----------------
__global__ void embed_k(const int* __restrict__ ids, const float* __restrict__ emb,
                        float* __restrict__ x) {
    int l = blockIdx.x;
    int id = ids[l];
    const float4* src = (const float4*)(emb + (size_t)id * DMODEL);
    float4* dst = (float4*)(x + (size_t)l * DMODEL);
    dst[threadIdx.x] = src[threadIdx.x];   // 256 threads * float4 = 1024 floats
}

// ---------------- RMSNorm (one block per row, 1024 elems) ----------------
__global__ void rmsnorm_k(const float* __restrict__ x, const float* __restrict__ w,
                          float* __restrict__ out) {
    int l = blockIdx.x;
    const float4* xr = (const float4*)(x + (size_t)l * DMODEL);
    float4 v = xr[threadIdx.x];
    float ss = v.x*v.x + v.y*v.y + v.z*v.z + v.w*v.w;
    for (int off = 32; off > 0; off >>= 1) ss += __shfl_down(ss, off, 64);
    __shared__ float sred[4];
    int wid = threadIdx.x >> 6;
    if ((threadIdx.x & 63) == 0) sred[wid] = ss;
    __syncthreads();
    float tot = sred[0] + sred[1] + sred[2] + sred[3];
    float scale = rsqrtf(tot * (1.0f / DMODEL) + 1e-5f);
    float4 wv = ((const float4*)w)[threadIdx.x];
    float4 o;
    o.x = v.x * scale * wv.x; o.y = v.y * scale * wv.y;
    o.z = v.z * scale * wv.z; o.w = v.w * scale * wv.w;
    ((float4*)(out + (size_t)l * DMODEL))[threadIdx.x] = o;
}

// ---------------- causal depthwise conv (k=4) + silu ----------------
// XR: [L, 2*DINNER]; xp = XR[:, :DINNER]. out: [L, DINNER]
__global__ void conv_silu_k(const float* __restrict__ XR, const float* __restrict__ w,
                            const float* __restrict__ b, float* __restrict__ out) {
    int idx = blockIdx.x * blockDim.x + threadIdx.x;
    int d = idx & (DINNER - 1);
    int l = idx >> 11;
    float4 wv = *(const float4*)(w + (size_t)d * 4);
    float acc = b[d];
    const float* col = XR + d;
    if (l >= 3) {
        acc += wv.x * col[(size_t)(l-3) * (2*DINNER)];
        acc += wv.y * col[(size_t)(l-2) * (2*DINNER)];
        acc += wv.z * col[(size_t)(l-1) * (2*DINNER)];
    } else {
        if (l-3 >= 0) acc += wv.x * col[(size_t)(l-3) * (2*DINNER)];
        if (l-2 >= 0) acc += wv.y * col[(size_t)(l-2) * (2*DINNER)];
        if (l-1 >= 0) acc += wv.z * col[(size_t)(l-1) * (2*DINNER)];
    }
    acc += wv.w * col[(size_t)l * (2*DINNER)];
    out[(size_t)l * DINNER + d] = silu_f(acc);
}

// ---------------- generic fp32 GEMM: C[M,N] = A[M,K] @ B[N,K]^T ----------------
// EPI: 0 = plain store, 1 = += E (residual, [M,ldc]), 2 = softplus(acc + E[n]) (bias)
template<int EPI, bool BNC>
__global__ __launch_bounds__(256) void gemm_bt_k(
    const float* __restrict__ A, const float* __restrict__ B, float* __restrict__ C,
    int M, int N, int K, int lda, int ldb, int ldc, const float* __restrict__ E)
{
    __shared__ float As[16][68];
    __shared__ float Bs[16][68];
    int m0 = blockIdx.y * 64;
    int n0 = blockIdx.x * 64;
    int t = threadIdx.x;
    int tx = t & 15, ty = t >> 4;
    int lrow = t >> 2;          // 0..63
    int lc = (t & 3) * 4;       // 0,4,8,12
    float acc[4][4] = {};

    for (int k0 = 0; k0 < K; k0 += 16) {
        float4 a4 = *(const float4*)(A + (size_t)(m0 + lrow) * lda + k0 + lc);
        As[lc + 0][lrow] = a4.x; As[lc + 1][lrow] = a4.y;
        As[lc + 2][lrow] = a4.z; As[lc + 3][lrow] = a4.w;
        float4 b4;
        if (BNC && (n0 + lrow >= N)) b4 = make_float4(0.f, 0.f, 0.f, 0.f);
        else b4 = *(const float4*)(B + (size_t)(n0 + lrow) * ldb + k0 + lc);
        Bs[lc + 0][lrow] = b4.x; Bs[lc + 1][lrow] = b4.y;
        Bs[lc + 2][lrow] = b4.z; Bs[lc + 3][lrow] = b4.w;
        __syncthreads();
#pragma unroll
        for (int k = 0; k < 16; ++k) {
            float4 av = *(const float4*)(&As[k][ty * 4]);
            float4 bv = *(const float4*)(&Bs[k][tx * 4]);
            acc[0][0] += av.x * bv.x; acc[0][1] += av.x * bv.y;
            acc[0][2] += av.x * bv.z; acc[0][3] += av.x * bv.w;
            acc[1][0] += av.y * bv.x; acc[1][1] += av.y * bv.y;
            acc[1][2] += av.y * bv.z; acc[1][3] += av.y * bv.w;
            acc[2][0] += av.z * bv.x; acc[2][1] += av.z * bv.y;
            acc[2][2] += av.z * bv.z; acc[2][3] += av.z * bv.w;
            acc[3][0] += av.w * bv.x; acc[3][1] += av.w * bv.y;
            acc[3][2] += av.w * bv.z; acc[3][3] += av.w * bv.w;
        }
        __syncthreads();
    }

    int n = n0 + tx * 4;
    if (BNC && n >= N) return;
#pragma unroll
    for (int i = 0; i < 4; ++i) {
        int m = m0 + ty * 4 + i;
        float4 r;
        r.x = acc[i][0]; r.y = acc[i][1]; r.z = acc[i][2]; r.w = acc[i][3];
        if (EPI == 1) {
            float4 e = *(const float4*)(E + (size_t)m * ldc + n);
            r.x += e.x; r.y += e.y; r.z += e.z; r.w += e.w;
        } else if (EPI == 2) {
            float4 bb = *(const float4*)(E + n);
            r.x = sp_softplus(r.x + bb.x); r.y = sp_softplus(r.y + bb.y);
            r.z = sp_softplus(r.z + bb.z); r.w = sp_softplus(r.w + bb.w);
        }
        *(float4*)(C + (size_t)m * ldc + n) = r;
    }
}

// ---------------- selective scan ----------------
// block: 256 threads = 16 channels x 16 states. grid: DINNER/16 = 128.
// yz[l,d] = (sum_n h*C + u*D) * silu(res)
__global__ __launch_bounds__(256) void scan_k(
    const float* __restrict__ delta, const float* __restrict__ u,
    const float* __restrict__ xdbl, const float* __restrict__ A_log,
    const float* __restrict__ Dp, const float* __restrict__ XR,
    float* __restrict__ yz)
{
    const int CH = 64;
    int d0 = blockIdx.x * 16;
    int t = threadIdx.x;
    int ci = t >> 4;       // channel within block
    int n  = t & 15;       // state index
    int d  = d0 + ci;
    float Av = -__expf(A_log[(size_t)d * DSTATE + n]);
    float Dv = Dp[d];
    float h = 0.f;

    __shared__ float sdel[CH][16];
    __shared__ float su[CH][16];
    __shared__ float sres[CH][16];
    __shared__ float sBC[CH][32];

    for (int l0 = 0; l0 < LSEQ; l0 += CH) {
        {
            int r = t >> 2, c = (t & 3) * 4;
            *(float4*)&sdel[r][c] = *(const float4*)(delta + (size_t)(l0 + r) * DINNER + d0 + c);
            *(float4*)&su[r][c]   = *(const float4*)(u     + (size_t)(l0 + r) * DINNER + d0 + c);
            *(float4*)&sres[r][c] = *(const float4*)(XR + (size_t)(l0 + r) * (2*DINNER) + DINNER + d0 + c);
        }
        for (int q = t; q < CH * 8; q += 256) {
            int r = q >> 3, c = (q & 7) * 4;
            *(float4*)&sBC[r][c] = *(const float4*)(xdbl + (size_t)(l0 + r) * 96 + DTRANK + c);
        }
        __syncthreads();
#pragma unroll 4
        for (int r = 0; r < CH; ++r) {
            float dl = sdel[r][ci];
            float uv = su[r][ci];
            float Bv = sBC[r][n];
            float Cv = sBC[r][16 + n];
            float dA = __expf(dl * Av);
            h = dA * h + dl * uv * Bv;
            float p = h * Cv;
            p += __shfl_xor(p, 1, 64);
            p += __shfl_xor(p, 2, 64);
            p += __shfl_xor(p, 4, 64);
            p += __shfl_xor(p, 8, 64);
            if (n == 0) {
                float y = p + uv * Dv;
                yz[(size_t)(l0 + r) * DINNER + d] = y * silu_f(sres[r][ci]);
            }
        }
        __syncthreads();
    }
}

extern "C" void kernel_launch(void* const* d_in, const int* in_sizes, int n_in,
                              void* d_out, int out_size, void* d_ws, size_t ws_size,
                              hipStream_t stream) {
    const int*   ids    = (const int*)  d_in[0];
    const float* emb    = (const float*)d_in[1];
    const float* in_w   = (const float*)d_in[2];   // [2,4096,1024]
    const float* conv_w = (const float*)d_in[3];   // [2,2048,1,4]
    const float* conv_b = (const float*)d_in[4];   // [2,2048]
    const float* xp_w   = (const float*)d_in[5];   // [2,96,2048]
    const float* dt_w   = (const float*)d_in[6];   // [2,2048,64]
    const float* dt_b   = (const float*)d_in[7];   // [2,2048]
    const float* A_log  = (const float*)d_in[8];   // [2,2048,16]
    const float* Dp     = (const float*)d_in[9];   // [2,2048]
    const float* out_w  = (const float*)d_in[10];  // [2,1024,2048]
    const float* nw     = (const float*)d_in[11];  // [2,1024]
    const float* nfw    = (const float*)d_in[12];  // [1024]
    float* out = (float*)d_out;

    float* ws    = (float*)d_ws;
    float* x     = ws;                    // [L,1024]
    float* h     = x     + (size_t)LSEQ * DMODEL;
    float* XR    = h     + (size_t)LSEQ * DMODEL;        // [L,4096]
    float* xconv = XR    + (size_t)LSEQ * 2 * DINNER;    // [L,2048]
    float* xdbl  = xconv + (size_t)LSEQ * DINNER;        // [L,96]
    float* delta = xdbl  + (size_t)LSEQ * 96;            // [L,2048]
    float* yz    = delta + (size_t)LSEQ * DINNER;        // [L,2048]

    embed_k<<<LSEQ, 256, 0, stream>>>(ids, emb, x);

    for (int i = 0; i < 2; ++i) {
        rmsnorm_k<<<LSEQ, 256, 0, stream>>>(x, nw + (size_t)i * DMODEL, h);
        // in_proj: [L,1024] @ [4096,1024]^T -> XR [L,4096]
        gemm_bt_k<0, false><<<dim3(4096/64, LSEQ/64), 256, 0, stream>>>(
            h, in_w + (size_t)i * 2*DINNER * DMODEL, XR,
            LSEQ, 2*DINNER, DMODEL, DMODEL, DMODEL, 2*DINNER, nullptr);
        conv_silu_k<<<(LSEQ * DINNER) / 256, 256, 0, stream>>>(
            XR, conv_w + (size_t)i * DINNER * 4, conv_b + (size_t)i * DINNER, xconv);
        // x_proj: [L,2048] @ [96,2048]^T -> xdbl [L,96]
        gemm_bt_k<0, true><<<dim3(2, LSEQ/64), 256, 0, stream>>>(
            xconv, xp_w + (size_t)i * 96 * DINNER, xdbl,
            LSEQ, 96, DINNER, DINNER, DINNER, 96, nullptr);
        // dt_proj + softplus: [L,64] @ [2048,64]^T -> delta [L,2048]
        gemm_bt_k<2, false><<<dim3(DINNER/64, LSEQ/64), 256, 0, stream>>>(
            xdbl, dt_w + (size_t)i * DINNER * DTRANK, delta,
            LSEQ, DINNER, DTRANK, 96, DTRANK, DINNER, dt_b + (size_t)i * DINNER);
        scan_k<<<DINNER/16, 256, 0, stream>>>(
            delta, xconv, xdbl, A_log + (size_t)i * DINNER * DSTATE,
            Dp + (size_t)i * DINNER, XR, yz);
        // out_proj + residual: [L,2048] @ [1024,2048]^T + x -> x
        gemm_bt_k<1, false><<<dim3(DMODEL/64, LSEQ/64), 256, 0, stream>>>(
            yz, out_w + (size_t)i * DMODEL * DINNER, x,
            LSEQ, DMODEL, DINNER, DINNER, DINNER, DMODEL, x);
    }

    rmsnorm_k<<<LSEQ, 256, 0, stream>>>(x, nfw, h);
    // logits: [L,1024] @ [50264,1024]^T -> out [L,50264]
    gemm_bt_k<0, true><<<dim3((NVOCAB + 63) / 64, LSEQ/64), 256, 0, stream>>>(
        h, emb, out, LSEQ, NVOCAB, DMODEL, DMODEL, DMODEL, NVOCAB, nullptr);
}